// Round 3
// baseline (431.267 us; speedup 1.0000x reference)
//
#include <hip/hip_runtime.h>

typedef unsigned short u16;
typedef unsigned int u32;
typedef unsigned long long u64;
typedef __attribute__((ext_vector_type(8))) short short8;
typedef __attribute__((ext_vector_type(4))) float f32x4;

#define NB 16
#define SL 512
#define HS 1024
#define NHEAD 16
#define HD 64

typedef const __attribute__((address_space(1))) u32* gas_t;
typedef __attribute__((address_space(3))) u32* las_t;

__device__ __forceinline__ void gld16(const u16* g, u16* l) {
  // async global->LDS, 16B/lane; LDS dest = wave-uniform base + lane*16
  __builtin_amdgcn_global_load_lds((gas_t)g, (las_t)l, 16, 0, 0);
}

__device__ __forceinline__ u16 f2bf(float f) {
  union { float f; unsigned u; } c; c.f = f;
  unsigned r = c.u + 0x7FFFu + ((c.u >> 16) & 1u);
  return (u16)(r >> 16);
}
__device__ __forceinline__ float bf2f(u16 u) {
  union { float f; unsigned u; } c; c.u = ((unsigned)u) << 16;
  return c.f;
}

// ---------------- fp32 -> bf16 convert ----------------
__global__ __launch_bounds__(256) void cvt_bf16(const float* __restrict__ in,
                                                u16* __restrict__ out, long n) {
  long i = ((long)blockIdx.x * 256 + threadIdx.x) * 4;
  if (i >= n) return;
  float4 f = *(const float4*)(in + i);
  uint2 u;
  u.x = (unsigned)f2bf(f.x) | ((unsigned)f2bf(f.y) << 16);
  u.y = (unsigned)f2bf(f.z) | ((unsigned)f2bf(f.w) << 16);
  *(uint2*)(out + i) = u;
}

__global__ __launch_bounds__(256) void cvt_w4(const float* __restrict__ a,
                                              const float* __restrict__ b,
                                              const float* __restrict__ c,
                                              const float* __restrict__ d,
                                              u16* __restrict__ o, long n) {
  const float* in = (blockIdx.y == 0) ? a : (blockIdx.y == 1) ? b
                     : (blockIdx.y == 2) ? c : d;
  u16* out = o + (long)blockIdx.y * n;
  long i = ((long)blockIdx.x * 256 + threadIdx.x) * 4;
  if (i >= n) return;
  float4 f = *(const float4*)(in + i);
  uint2 u;
  u.x = (unsigned)f2bf(f.x) | ((unsigned)f2bf(f.y) << 16);
  u.y = (unsigned)f2bf(f.z) | ((unsigned)f2bf(f.w) << 16);
  *(uint2*)(out + i) = u;
}

// ---------------- mask int32 -> bitmask ----------------
__global__ __launch_bounds__(256) void pack_mask(const int* __restrict__ m0,
                                                 const int* __restrict__ m1,
                                                 u64* __restrict__ o0,
                                                 u64* __restrict__ o1, long n) {
  long i = (long)blockIdx.x * 256 + threadIdx.x;
  const int* m = blockIdx.y ? m1 : m0;
  u64* o = blockIdx.y ? o1 : o0;
  u64 bits = __ballot(m[i] != 0);
  if ((threadIdx.x & 63) == 0) o[i >> 6] = bits;
}

// ---------------- GEMM: C[M,N] = A[M,K] @ W[N,K]^T, bf16 ----------------
// 64x128 tile, BK=64, grid (M/64, N/128) = 1024 blocks -> 4 blocks/CU
// (grid was the occupancy binder at 128x128). 4 waves 2x2, wave tile 32x64.
// gld16 staging into cb^row xor layout; frag reads conflict-free.
template<bool CF32>
__global__ __launch_bounds__(256, 4) void gemm_bt(const u16* __restrict__ A,
                                                  const u16* __restrict__ W,
                                                  void* __restrict__ C,
                                                  int M, int N, int K) {
  __shared__ u16 As[64 * 64];
  __shared__ u16 Bs[128 * 64];
  const int tid = threadIdx.x;
  const int wave = tid >> 6, lane = tid & 63;
  const int quad = lane >> 4, l16 = lane & 15;
  const int l7 = l16 & 7;
  const int row0 = blockIdx.x * 64, col0 = blockIdx.y * 128;
  const int wm = (wave >> 1) * 32, wn = (wave & 1) * 64;
  const int lrow = lane >> 3;
  const int scb = (lane & 7) ^ lrow;

  f32x4 acc[2][4];
#pragma unroll
  for (int mt = 0; mt < 2; ++mt)
#pragma unroll
    for (int nt = 0; nt < 4; ++nt) acc[mt][nt] = (f32x4){0.f, 0.f, 0.f, 0.f};

  const u16* Ab = A + (long)row0 * K;
  const u16* Wb = W + (long)col0 * K;

  for (int k0 = 0; k0 < K; k0 += 64) {
    __syncthreads();
#pragma unroll
    for (int it = 0; it < 2; ++it) {  // A: 8 segments of 8 rows
      int seg = wave * 2 + it;
      gld16(Ab + (long)(seg * 8 + lrow) * K + k0 + scb * 8, As + seg * 512);
    }
#pragma unroll
    for (int it = 0; it < 4; ++it) {  // W: 16 segments
      int seg = wave * 4 + it;
      gld16(Wb + (long)(seg * 8 + lrow) * K + k0 + scb * 8, Bs + seg * 512);
    }
    __syncthreads();
#pragma unroll
    for (int kt = 0; kt < 2; ++kt) {
      short8 af[2], bw[4];
#pragma unroll
      for (int mt = 0; mt < 2; ++mt)
        af[mt] = *(const short8*)(As + (wm + mt * 16 + l16) * 64 +
                                  (((kt * 4 + quad) ^ l7) * 8));
#pragma unroll
      for (int nt = 0; nt < 4; ++nt)
        bw[nt] = *(const short8*)(Bs + (wn + nt * 16 + l16) * 64 +
                                  (((kt * 4 + quad) ^ l7) * 8));
#pragma unroll
      for (int mt = 0; mt < 2; ++mt)
#pragma unroll
        for (int nt = 0; nt < 4; ++nt)
          acc[mt][nt] = __builtin_amdgcn_mfma_f32_16x16x32_bf16(
              af[mt], bw[nt], acc[mt][nt], 0, 0, 0);
    }
  }
#pragma unroll
  for (int mt = 0; mt < 2; ++mt)
#pragma unroll
    for (int nt = 0; nt < 4; ++nt)
#pragma unroll
      for (int i = 0; i < 4; ++i) {
        long r = row0 + wm + mt * 16 + quad * 4 + i;
        long c = col0 + wn + nt * 16 + l16;
        float v = acc[mt][nt][i];
        if constexpr (CF32)
          ((float*)C)[r * N + c] = v;
        else
          ((u16*)C)[r * N + c] = f2bf(v);
      }
}

// ---------------- fused masked attention ----------------
// One block = (b, h, 128-q rows), 8 key tiles of 64. 4 waves, each wave owns
// 32 q-rows (2 row-frags). Q A-frags live in REGISTERS (no Qs LDS; residual
// re-reads Q from warm cache). K staged via gld16 (xor-cb layout). V staged
// transposed w/ conflict-free vxor. P via LDS pitch-72, no xor (reads clean,
// writes 2-way). No-max softmax (logits ~ +-4; masked -> p=0 exactly).
__global__ __launch_bounds__(256) void attn(const u16* __restrict__ Qp,
                                            const u16* __restrict__ Kp,
                                            const u16* __restrict__ Vp,
                                            const u32* __restrict__ Bits,
                                            u16* __restrict__ Op,
                                            int residual) {
  __shared__ u16 Ks[64 * 64];   // gld16 cb^row layout
  __shared__ u16 Vs[64][72];    // row=d, col = key ^ (((d>>4)&3)<<4)
  __shared__ u16 Ps[128][72];   // plain pitch-72
  const int tid = threadIdx.x;
  const int wave = tid >> 6, lane = tid & 63;
  const int quad = lane >> 4, l16 = lane & 15;
  const int l7 = l16 & 7;
  const int qt = blockIdx.x, h = blockIdx.y, b = blockIdx.z;
  const int q0 = qt * 128;
  const long bs = (long)SL * HS;
  const u16* Qb = Qp + (long)b * bs + h * HD;
  const u16* Kb = Kp + (long)b * bs + h * HD;
  const u16* Vb = Vp + (long)b * bs + h * HD;
  const u32* Mb = Bits + (long)b * SL * 16;  // 16 u32 words per row
  const int lrow = lane >> 3;
  const int scb = (lane & 7) ^ lrow;

  // ---- Q A-frags -> registers (one-time) ----
  short8 qf[2][2];
#pragma unroll
  for (int rf = 0; rf < 2; ++rf)
#pragma unroll
    for (int kt = 0; kt < 2; ++kt) {
      int row = q0 + wave * 32 + rf * 16 + l16;
      qf[rf][kt] = *(const short8*)(Qb + (long)row * HS + kt * 32 + quad * 8);
    }

  float l_i[2][4];
  f32x4 o[2][4];
#pragma unroll
  for (int rf = 0; rf < 2; ++rf)
#pragma unroll
    for (int nt = 0; nt < 4; ++nt) {
      o[rf][nt] = (f32x4){0.f, 0.f, 0.f, 0.f};
      l_i[rf][nt] = 0.f;
    }

  const int sr = tid >> 2, sds = (tid & 3) * 16;
  const int vcol = sr ^ (((sds >> 4) & 3) << 4);

  for (int t = 0; t < 8; ++t) {
    const int k0 = t * 64;
    __syncthreads();
#pragma unroll
    for (int it = 0; it < 2; ++it) {  // K: 8 segments of 8 rows
      int seg = wave * 2 + it;
      gld16(Kb + (long)(k0 + seg * 8 + lrow) * HS + scb * 8, Ks + seg * 512);
    }
    {  // V transposed + swizzled
      uint4 v0 = *(const uint4*)(Vb + (long)(k0 + sr) * HS + sds);
      uint4 v1 = *(const uint4*)(Vb + (long)(k0 + sr) * HS + sds + 8);
      union { uint4 q[2]; u16 e[16]; } tv;
      tv.q[0] = v0; tv.q[1] = v1;
#pragma unroll
      for (int j = 0; j < 16; ++j) Vs[sds + j][vcol] = tv.e[j];
    }
    __syncthreads();
    // ---- S = Q K^T ----
    f32x4 s[2][4];
#pragma unroll
    for (int rf = 0; rf < 2; ++rf)
#pragma unroll
      for (int nt = 0; nt < 4; ++nt) s[rf][nt] = (f32x4){0.f, 0.f, 0.f, 0.f};
#pragma unroll
    for (int kt = 0; kt < 2; ++kt)
#pragma unroll
      for (int nt = 0; nt < 4; ++nt) {
        short8 bk = *(const short8*)(Ks + (nt * 16 + l16) * 64 +
                                     (((kt * 4 + quad) ^ l7) * 8));
#pragma unroll
        for (int rf = 0; rf < 2; ++rf)
          s[rf][nt] = __builtin_amdgcn_mfma_f32_16x16x32_bf16(qf[rf][kt], bk,
                                                              s[rf][nt], 0, 0, 0);
      }
    // ---- mask bits + exp + P write ----
#pragma unroll
    for (int rf = 0; rf < 2; ++rf)
#pragma unroll
      for (int i = 0; i < 4; ++i) {
        int gr = q0 + wave * 32 + rf * 16 + quad * 4 + i;
        uint2 mw = *(const uint2*)&Mb[(long)gr * 16 + t * 2];
#pragma unroll
        for (int nt = 0; nt < 4; ++nt) {
          u32 w = (nt & 2) ? mw.y : mw.x;
          int msk = (w >> ((nt & 1) * 16 + l16)) & 1;
          float p = msk ? 0.f : __expf(s[rf][nt][i] * 0.125f);
          l_i[rf][i] += p;
          Ps[wave * 32 + rf * 16 + quad * 4 + i][nt * 16 + l16] = f2bf(p);
        }
      }
    __syncthreads();
    // ---- O += P V ----
#pragma unroll
    for (int kt = 0; kt < 2; ++kt) {
      short8 ap[2];
#pragma unroll
      for (int rf = 0; rf < 2; ++rf)
        ap[rf] = *(const short8*)&Ps[wave * 32 + rf * 16 + l16]
                                    [kt * 32 + quad * 8];
#pragma unroll
      for (int nt = 0; nt < 4; ++nt) {
        short8 bv = *(const short8*)&Vs[nt * 16 + l16]
                                      [(kt * 32 + quad * 8) ^ ((nt & 3) << 4)];
#pragma unroll
        for (int rf = 0; rf < 2; ++rf)
          o[rf][nt] = __builtin_amdgcn_mfma_f32_16x16x32_bf16(ap[rf], bv,
                                                              o[rf][nt], 0, 0, 0);
      }
    }
  }
  // ---- epilogue ----
  u16* Ob = Op + (long)b * bs + h * HD;
#pragma unroll
  for (int rf = 0; rf < 2; ++rf)
#pragma unroll
    for (int i = 0; i < 4; ++i) {
      float rs = l_i[rf][i];
#pragma unroll
      for (int off = 8; off >= 1; off >>= 1) rs += __shfl_xor(rs, off, 64);
      float inv = 1.f / rs;
      int r = q0 + wave * 32 + rf * 16 + quad * 4 + i;
#pragma unroll
      for (int nt = 0; nt < 4; ++nt) {
        float val = o[rf][nt][i] * inv;
        if (residual) val += bf2f(Qb[(long)r * HS + nt * 16 + l16]);
        Ob[(long)r * HS + nt * 16 + l16] = f2bf(val);
      }
    }
}

extern "C" void kernel_launch(void* const* d_in, const int* in_sizes, int n_in,
                              void* d_out, int out_size, void* d_ws,
                              size_t ws_size, hipStream_t stream) {
  const float* v   = (const float*)d_in[0];
  const float* k   = (const float*)d_in[1];
  const float* q   = (const float*)d_in[2];
  const float* img = (const float*)d_in[3];
  const float* Wv  = (const float*)d_in[4];
  const float* Wk  = (const float*)d_in[5];
  const float* Wq  = (const float*)d_in[6];
  const float* Wm  = (const float*)d_in[7];
  const int* absm  = (const int*)d_in[8];
  const int* mask  = (const int*)d_in[9];
  float* out = (float*)d_out;

  const long NTOK = (long)NB * SL * HS;    // 8,388,608
  const long NW   = (long)HS * HS;         // 1,048,576
  const long NM   = (long)NB * SL * SL;    // 4,194,304
  u16* ws  = (u16*)d_ws;
  u16* xb  = ws;              // staging A (v/k/q bf16), later qm
  u16* pb  = ws + 1 * NTOK;   // img_abs bf16
  u16* vh  = ws + 2 * NTOK;
  u16* kh  = ws + 3 * NTOK;
  u16* qh  = ws + 4 * NTOK;   // later att
  u16* w4  = ws + 5 * NTOK;
  u64* bt0 = (u64*)(w4 + 4 * NW);
  u64* bt1 = bt0 + NM / 64;
  u16* qm  = xb;
  u16* att = qh;

  dim3 gg(NB * SL / 64, HS / 128);   // (128, 8) = 1024 blocks
  dim3 ga(SL / 128, NHEAD, NB);      // (4, 16, 16) = 1024 blocks

  cvt_bf16<<<(unsigned)(NTOK / 1024), 256, 0, stream>>>(img, pb, NTOK);
  cvt_w4<<<dim3((unsigned)(NW / 1024), 4), 256, 0, stream>>>(Wv, Wk, Wq, Wm, w4, NW);
  pack_mask<<<dim3((unsigned)(NM / 256), 2), 256, 0, stream>>>(absm, mask, bt0, bt1, NM);

  cvt_bf16<<<(unsigned)(NTOK / 1024), 256, 0, stream>>>(v, xb, NTOK);
  gemm_bt<false><<<gg, 256, 0, stream>>>(xb, w4 + 0 * NW, vh, NB * SL, HS, HS);
  cvt_bf16<<<(unsigned)(NTOK / 1024), 256, 0, stream>>>(k, xb, NTOK);
  gemm_bt<false><<<gg, 256, 0, stream>>>(xb, w4 + 1 * NW, kh, NB * SL, HS, HS);
  cvt_bf16<<<(unsigned)(NTOK / 1024), 256, 0, stream>>>(q, xb, NTOK);
  gemm_bt<false><<<gg, 256, 0, stream>>>(xb, w4 + 2 * NW, qh, NB * SL, HS, HS);

  attn<<<ga, 256, 0, stream>>>(qh, pb, pb, (const u32*)bt0, qm, 1);
  attn<<<ga, 256, 0, stream>>>(qm, kh, vh, (const u32*)bt1, att, 0);

  gemm_bt<true><<<gg, 256, 0, stream>>>(att, w4 + 3 * NW, out, NB * SL, HS, HS);
}

// Round 4
// 425.521 us; speedup vs baseline: 1.0135x; 1.0135x over previous
//
#include <hip/hip_runtime.h>

typedef unsigned short u16;
typedef unsigned int u32;
typedef unsigned long long u64;
typedef __attribute__((ext_vector_type(8))) short short8;
typedef __attribute__((ext_vector_type(4))) float f32x4;

#define NB 16
#define SL 512
#define HS 1024
#define NHEAD 16
#define HD 64
#define NTOKC (16L * 512 * 1024)   // NB*SL*HS
#define NWC   (1024L * 1024)       // HS*HS

typedef const __attribute__((address_space(1))) u32* gas_t;
typedef __attribute__((address_space(3))) u32* las_t;

__device__ __forceinline__ void gld16(const u16* g, u16* l) {
  __builtin_amdgcn_global_load_lds((gas_t)g, (las_t)l, 16, 0, 0);
}

__device__ __forceinline__ u16 f2bf(float f) {
  union { float f; unsigned u; } c; c.f = f;
  unsigned r = c.u + 0x7FFFu + ((c.u >> 16) & 1u);
  return (u16)(r >> 16);
}
__device__ __forceinline__ float bf2f(u16 u) {
  union { float f; unsigned u; } c; c.u = ((unsigned)u) << 16;
  return c.f;
}

// ---------------- fused fp32 -> bf16 convert: v, k, q, img ----------------
__global__ __launch_bounds__(256) void cvt4(const float* __restrict__ v,
                                            const float* __restrict__ k,
                                            const float* __restrict__ q,
                                            const float* __restrict__ img,
                                            u16* __restrict__ ovk,
                                            u16* __restrict__ xq,
                                            u16* __restrict__ pb, long n) {
  int which = blockIdx.y;
  const float* in = which == 0 ? v : which == 1 ? k : which == 2 ? q : img;
  u16* out = which == 0 ? ovk : which == 1 ? ovk + n : which == 2 ? xq : pb;
  long i = ((long)blockIdx.x * 256 + threadIdx.x) * 4;
  if (i >= n) return;
  float4 f = *(const float4*)(in + i);
  uint2 u;
  u.x = (unsigned)f2bf(f.x) | ((unsigned)f2bf(f.y) << 16);
  u.y = (unsigned)f2bf(f.z) | ((unsigned)f2bf(f.w) << 16);
  *(uint2*)(out + i) = u;
}

__global__ __launch_bounds__(256) void cvt_w4(const float* __restrict__ a,
                                              const float* __restrict__ b,
                                              const float* __restrict__ c,
                                              const float* __restrict__ d,
                                              u16* __restrict__ o, long n) {
  const float* in = (blockIdx.y == 0) ? a : (blockIdx.y == 1) ? b
                     : (blockIdx.y == 2) ? c : d;
  u16* out = o + (long)blockIdx.y * n;
  long i = ((long)blockIdx.x * 256 + threadIdx.x) * 4;
  if (i >= n) return;
  float4 f = *(const float4*)(in + i);
  uint2 u;
  u.x = (unsigned)f2bf(f.x) | ((unsigned)f2bf(f.y) << 16);
  u.y = (unsigned)f2bf(f.z) | ((unsigned)f2bf(f.w) << 16);
  *(uint2*)(out + i) = u;
}

__global__ __launch_bounds__(256) void pack_mask(const int* __restrict__ m0,
                                                 const int* __restrict__ m1,
                                                 u64* __restrict__ o0,
                                                 u64* __restrict__ o1, long n) {
  long i = (long)blockIdx.x * 256 + threadIdx.x;
  const int* m = blockIdx.y ? m1 : m0;
  u64* o = blockIdx.y ? o1 : o0;
  u64 bits = __ballot(m[i] != 0);
  if ((threadIdx.x & 63) == 0) o[i >> 6] = bits;
}

// ------- triple-batched projection GEMM: {v,k,q} @ {Wv,Wk,Wq}^T ----------
// 128x128 tile, BK=64. grid (192, 8) = 1536 blocks -> 6/CU dispatched.
// sel = blockIdx.x>>6 picks operand set; v/k A-stage lives in d_out, q in ws.
__global__ __launch_bounds__(256) void gemm_p3(const u16* __restrict__ Avk,
                                               const u16* __restrict__ Aq,
                                               const u16* __restrict__ W4,
                                               u16* __restrict__ Cb) {
  __shared__ u16 As[128 * 64];
  __shared__ u16 Bs[128 * 64];
  const int tid = threadIdx.x;
  const int wave = tid >> 6, lane = tid & 63;
  const int quad = lane >> 4, l16 = lane & 15;
  const int l7 = l16 & 7;
  const int sel = blockIdx.x >> 6;
  const int row0 = (blockIdx.x & 63) * 128, col0 = blockIdx.y * 128;
  const int wm = (wave >> 1) * 64, wn = (wave & 1) * 64;
  const int lrow = lane >> 3;
  const int scb = (lane & 7) ^ lrow;
  const int K = HS, N = HS;

  const u16* A = (sel == 2) ? Aq : Avk + (long)sel * NTOKC;
  const u16* W = W4 + (long)sel * NWC;
  u16* C = Cb + (long)sel * NTOKC;

  f32x4 acc[4][4];
#pragma unroll
  for (int mt = 0; mt < 4; ++mt)
#pragma unroll
    for (int nt = 0; nt < 4; ++nt) acc[mt][nt] = (f32x4){0.f, 0.f, 0.f, 0.f};

  const u16* Ab = A + (long)row0 * K;
  const u16* Wb = W + (long)col0 * K;

  for (int k0 = 0; k0 < K; k0 += 64) {
    __syncthreads();
#pragma unroll
    for (int it = 0; it < 4; ++it) {
      int seg = wave * 4 + it;
      int r = seg * 8 + lrow;
      gld16(Ab + (long)r * K + k0 + scb * 8, As + seg * 512);
      gld16(Wb + (long)r * K + k0 + scb * 8, Bs + seg * 512);
    }
    __syncthreads();
#pragma unroll
    for (int kt = 0; kt < 2; ++kt) {
      short8 af[4], bw[4];
#pragma unroll
      for (int mt = 0; mt < 4; ++mt)
        af[mt] = *(const short8*)(As + (wm + mt * 16 + l16) * 64 +
                                  (((kt * 4 + quad) ^ l7) * 8));
#pragma unroll
      for (int nt = 0; nt < 4; ++nt)
        bw[nt] = *(const short8*)(Bs + (wn + nt * 16 + l16) * 64 +
                                  (((kt * 4 + quad) ^ l7) * 8));
#pragma unroll
      for (int mt = 0; mt < 4; ++mt)
#pragma unroll
        for (int nt = 0; nt < 4; ++nt)
          acc[mt][nt] = __builtin_amdgcn_mfma_f32_16x16x32_bf16(
              af[mt], bw[nt], acc[mt][nt], 0, 0, 0);
    }
  }
#pragma unroll
  for (int mt = 0; mt < 4; ++mt)
#pragma unroll
    for (int nt = 0; nt < 4; ++nt)
#pragma unroll
      for (int i = 0; i < 4; ++i) {
        long r = row0 + wm + mt * 16 + quad * 4 + i;
        long c = col0 + wn + nt * 16 + l16;
        C[r * N + c] = f2bf(acc[mt][nt][i]);
      }
}

// ---------------- final GEMM: out[f32] = att @ Wm^T, 64x128 tile ----------
__global__ __launch_bounds__(256, 4) void gemm_f(const u16* __restrict__ A,
                                                 const u16* __restrict__ W,
                                                 float* __restrict__ C) {
  __shared__ u16 As[64 * 64];
  __shared__ u16 Bs[128 * 64];
  const int tid = threadIdx.x;
  const int wave = tid >> 6, lane = tid & 63;
  const int quad = lane >> 4, l16 = lane & 15;
  const int l7 = l16 & 7;
  const int row0 = blockIdx.x * 64, col0 = blockIdx.y * 128;
  const int wm = (wave >> 1) * 32, wn = (wave & 1) * 64;
  const int lrow = lane >> 3;
  const int scb = (lane & 7) ^ lrow;
  const int K = HS, N = HS;

  f32x4 acc[2][4];
#pragma unroll
  for (int mt = 0; mt < 2; ++mt)
#pragma unroll
    for (int nt = 0; nt < 4; ++nt) acc[mt][nt] = (f32x4){0.f, 0.f, 0.f, 0.f};

  const u16* Ab = A + (long)row0 * K;
  const u16* Wb = W + (long)col0 * K;

  for (int k0 = 0; k0 < K; k0 += 64) {
    __syncthreads();
#pragma unroll
    for (int it = 0; it < 2; ++it) {
      int seg = wave * 2 + it;
      gld16(Ab + (long)(seg * 8 + lrow) * K + k0 + scb * 8, As + seg * 512);
    }
#pragma unroll
    for (int it = 0; it < 4; ++it) {
      int seg = wave * 4 + it;
      gld16(Wb + (long)(seg * 8 + lrow) * K + k0 + scb * 8, Bs + seg * 512);
    }
    __syncthreads();
#pragma unroll
    for (int kt = 0; kt < 2; ++kt) {
      short8 af[2], bw[4];
#pragma unroll
      for (int mt = 0; mt < 2; ++mt)
        af[mt] = *(const short8*)(As + (wm + mt * 16 + l16) * 64 +
                                  (((kt * 4 + quad) ^ l7) * 8));
#pragma unroll
      for (int nt = 0; nt < 4; ++nt)
        bw[nt] = *(const short8*)(Bs + (wn + nt * 16 + l16) * 64 +
                                  (((kt * 4 + quad) ^ l7) * 8));
#pragma unroll
      for (int mt = 0; mt < 2; ++mt)
#pragma unroll
        for (int nt = 0; nt < 4; ++nt)
          acc[mt][nt] = __builtin_amdgcn_mfma_f32_16x16x32_bf16(
              af[mt], bw[nt], acc[mt][nt], 0, 0, 0);
    }
  }
#pragma unroll
  for (int mt = 0; mt < 2; ++mt)
#pragma unroll
    for (int nt = 0; nt < 4; ++nt)
#pragma unroll
      for (int i = 0; i < 4; ++i) {
        long r = row0 + wm + mt * 16 + quad * 4 + i;
        long c = col0 + wn + nt * 16 + l16;
        C[r * N + c] = acc[mt][nt][i];
      }
}

// ---------------- fused masked attention (R2 shape + Q-in-regs) -----------
// One block = (b, h, 64-q rows), 2048 blocks. LDS 27.6KB -> 5 blocks/CU.
// Q A-frags in registers (residual reloads Q from L2). K/V staged via
// register uint4 loads (known-good). No-max softmax; masked -> p=0 exactly.
__global__ __launch_bounds__(256) void attn(const u16* __restrict__ Qp,
                                            const u16* __restrict__ Kp,
                                            const u16* __restrict__ Vp,
                                            const u32* __restrict__ Bits,
                                            u16* __restrict__ Op,
                                            int residual) {
  __shared__ u16 Ks[64][72];
  __shared__ u16 Vs[64][72];  // row=d, col = key ^ (((d>>4)&3)<<4)
  __shared__ u16 Ps[64][72];  // plain pitch-72
  const int tid = threadIdx.x;
  const int wave = tid >> 6, lane = tid & 63;
  const int quad = lane >> 4, l16 = lane & 15;
  const int qt = blockIdx.x, h = blockIdx.y, b = blockIdx.z;
  const int q0 = qt * 64;
  const long bs = (long)SL * HS;
  const u16* Qb = Qp + (long)b * bs + h * HD;
  const u16* Kb = Kp + (long)b * bs + h * HD;
  const u16* Vb = Vp + (long)b * bs + h * HD;
  const u32* Mb = Bits + (long)b * SL * 16;

  // Q A-frags -> registers (one-time)
  short8 qf[2];
#pragma unroll
  for (int kt = 0; kt < 2; ++kt) {
    int row = q0 + wave * 16 + l16;
    qf[kt] = *(const short8*)(Qb + (long)row * HS + kt * 32 + quad * 8);
  }

  float l_i[4] = {0.f, 0.f, 0.f, 0.f};
  f32x4 o[4];
#pragma unroll
  for (int nt = 0; nt < 4; ++nt) o[nt] = (f32x4){0.f, 0.f, 0.f, 0.f};

  const int sr = tid >> 2, sds = (tid & 3) * 16;
  const int vcol = sr ^ (((sds >> 4) & 3) << 4);

  for (int t = 0; t < 8; ++t) {
    const int k0 = t * 64;
    __syncthreads();
    {
      const uint4* sk = (const uint4*)(Kb + (long)(k0 + sr) * HS + sds);
      *(uint4*)&Ks[sr][sds] = sk[0];
      *(uint4*)&Ks[sr][sds + 8] = sk[1];
      uint4 v0 = *(const uint4*)(Vb + (long)(k0 + sr) * HS + sds);
      uint4 v1 = *(const uint4*)(Vb + (long)(k0 + sr) * HS + sds + 8);
      union { uint4 q[2]; u16 e[16]; } tv;
      tv.q[0] = v0; tv.q[1] = v1;
#pragma unroll
      for (int j = 0; j < 16; ++j) Vs[sds + j][vcol] = tv.e[j];
    }
    __syncthreads();
    // S = Q K^T
    f32x4 s[4];
#pragma unroll
    for (int nt = 0; nt < 4; ++nt) s[nt] = (f32x4){0.f, 0.f, 0.f, 0.f};
#pragma unroll
    for (int kt = 0; kt < 2; ++kt)
#pragma unroll
      for (int nt = 0; nt < 4; ++nt) {
        short8 bk = *(const short8*)&Ks[nt * 16 + l16][kt * 32 + quad * 8];
        s[nt] = __builtin_amdgcn_mfma_f32_16x16x32_bf16(qf[kt], bk, s[nt], 0, 0, 0);
      }
    // mask bits + exp + P write
#pragma unroll
    for (int i = 0; i < 4; ++i) {
      int gr = q0 + wave * 16 + quad * 4 + i;
      uint2 mw = *(const uint2*)&Mb[(long)gr * 16 + t * 2];
#pragma unroll
      for (int nt = 0; nt < 4; ++nt) {
        u32 w = (nt & 2) ? mw.y : mw.x;
        int msk = (w >> ((nt & 1) * 16 + l16)) & 1;
        float p = msk ? 0.f : __expf(s[nt][i] * 0.125f);
        l_i[i] += p;
        Ps[wave * 16 + quad * 4 + i][nt * 16 + l16] = f2bf(p);
      }
    }
    __syncthreads();
    // O += P V
#pragma unroll
    for (int kt = 0; kt < 2; ++kt) {
      short8 ap = *(const short8*)&Ps[wave * 16 + l16][kt * 32 + quad * 8];
#pragma unroll
      for (int nt = 0; nt < 4; ++nt) {
        short8 bv = *(const short8*)&Vs[nt * 16 + l16]
                                      [(kt * 32 + quad * 8) ^ ((nt & 3) << 4)];
        o[nt] = __builtin_amdgcn_mfma_f32_16x16x32_bf16(ap, bv, o[nt], 0, 0, 0);
      }
    }
  }
  // epilogue
  u16* Ob = Op + (long)b * bs + h * HD;
#pragma unroll
  for (int i = 0; i < 4; ++i) {
    float rs = l_i[i];
#pragma unroll
    for (int off = 8; off >= 1; off >>= 1) rs += __shfl_xor(rs, off, 64);
    float inv = 1.f / rs;
    int r = q0 + wave * 16 + quad * 4 + i;
#pragma unroll
    for (int nt = 0; nt < 4; ++nt) {
      float val = o[nt][i] * inv;
      if (residual) val += bf2f(Qb[(long)r * HS + nt * 16 + l16]);
      Ob[(long)r * HS + nt * 16 + l16] = f2bf(val);
    }
  }
}

extern "C" void kernel_launch(void* const* d_in, const int* in_sizes, int n_in,
                              void* d_out, int out_size, void* d_ws,
                              size_t ws_size, hipStream_t stream) {
  const float* v   = (const float*)d_in[0];
  const float* k   = (const float*)d_in[1];
  const float* q   = (const float*)d_in[2];
  const float* img = (const float*)d_in[3];
  const float* Wv  = (const float*)d_in[4];
  const float* Wk  = (const float*)d_in[5];
  const float* Wq  = (const float*)d_in[6];
  const float* Wm  = (const float*)d_in[7];
  const int* absm  = (const int*)d_in[8];
  const int* mask  = (const int*)d_in[9];
  float* out = (float*)d_out;

  const long NTOK = NTOKC;                 // 8,388,608
  const long NW   = NWC;                   // 1,048,576
  const long NM   = (long)NB * SL * SL;    // 4,194,304
  // d_out (33.5 MB fp32) doubles as bf16 staging for v,k (2 x NTOK u16),
  // consumed by gemm_p3 before gemm_f overwrites it.
  u16* ovk = (u16*)d_out;
  u16* ws  = (u16*)d_ws;
  u16* xq  = ws;              // q bf16 staging; later qm
  u16* pb  = ws + 1 * NTOK;   // img_abs bf16
  u16* vh  = ws + 2 * NTOK;   // vh,kh,qh contiguous (gemm_p3 C base)
  u16* kh  = ws + 3 * NTOK;
  u16* qh  = ws + 4 * NTOK;   // later att
  u16* w4  = ws + 5 * NTOK;
  u64* bt0 = (u64*)(w4 + 4 * NW);
  u64* bt1 = bt0 + NM / 64;
  u16* qm  = xq;
  u16* att = qh;

  cvt4<<<dim3((unsigned)(NTOK / 1024), 4), 256, 0, stream>>>(v, k, q, img,
                                                             ovk, xq, pb, NTOK);
  cvt_w4<<<dim3((unsigned)(NW / 1024), 4), 256, 0, stream>>>(Wv, Wk, Wq, Wm, w4, NW);
  pack_mask<<<dim3((unsigned)(NM / 256), 2), 256, 0, stream>>>(absm, mask, bt0, bt1, NM);

  // 3 projections in one dispatch: 1536 blocks of 128x128
  gemm_p3<<<dim3(192, 8), 256, 0, stream>>>(ovk, xq, w4, vh);

  dim3 ga(SL / 64, NHEAD, NB);  // 2048 blocks
  attn<<<ga, 256, 0, stream>>>(qh, pb, pb, (const u32*)bt0, qm, 1);
  attn<<<ga, 256, 0, stream>>>(qm, kh, vh, (const u32*)bt1, att, 0);

  // final projection: 1024 blocks of 64x128, fp32 out (overwrites staging)
  gemm_f<<<dim3(NB * SL / 64, HS / 128), 256, 0, stream>>>(att, w4 + 3 * NW, out);
}

// Round 5
// 385.047 us; speedup vs baseline: 1.1200x; 1.1051x over previous
//
#include <hip/hip_runtime.h>

typedef unsigned short u16;
typedef unsigned int u32;
typedef unsigned long long u64;
typedef __attribute__((ext_vector_type(8))) short short8;
typedef __attribute__((ext_vector_type(4))) float f32x4;

#define NB 16
#define SL 512
#define HS 1024
#define NHEAD 16
#define HD 64
#define NTOKC (16L * 512 * 1024)   // NB*SL*HS = 8,388,608
#define NWC   (1024L * 1024)       // HS*HS    = 1,048,576 (2^20)
#define NMC   (16L * 512 * 512)    // NB*SL*SL = 4,194,304 (2^22)

typedef const __attribute__((address_space(1))) u32* gas_t;
typedef __attribute__((address_space(3))) u32* las_t;

__device__ __forceinline__ void gld16(const u16* g, u16* l) {
  __builtin_amdgcn_global_load_lds((gas_t)g, (las_t)l, 16, 0, 0);
}

__device__ __forceinline__ u16 f2bf(float f) {
  union { float f; unsigned u; } c; c.f = f;
  unsigned r = c.u + 0x7FFFu + ((c.u >> 16) & 1u);
  return (u16)(r >> 16);
}
__device__ __forceinline__ float bf2f(u16 u) {
  union { float f; unsigned u; } c; c.u = ((unsigned)u) << 16;
  return c.f;
}

// ---------------- unified prep: cvt v/k/q/img + 4 weights + mask pack -----
// grid (8192, 6): y=0..3 tensors, y=4 weights (guard 4096), y=5 masks (x4 reps)
__global__ __launch_bounds__(256) void prep(
    const float* __restrict__ v, const float* __restrict__ k,
    const float* __restrict__ q, const float* __restrict__ img,
    const float* __restrict__ Wv, const float* __restrict__ Wk,
    const float* __restrict__ Wq, const float* __restrict__ Wm,
    const int* __restrict__ absm, const int* __restrict__ mask,
    u16* __restrict__ ovk, u16* __restrict__ xq, u16* __restrict__ pb,
    u16* __restrict__ w4, u64* __restrict__ bits) {
  const int y = blockIdx.y;
  const long bx = blockIdx.x;
  if (y < 4) {
    const float* in = y == 0 ? v : y == 1 ? k : y == 2 ? q : img;
    u16* out = y == 0 ? ovk : y == 1 ? ovk + NTOKC : y == 2 ? xq : pb;
    long i = (bx * 256 + threadIdx.x) * 4;
    float4 f = *(const float4*)(in + i);
    uint2 u;
    u.x = (unsigned)f2bf(f.x) | ((unsigned)f2bf(f.y) << 16);
    u.y = (unsigned)f2bf(f.z) | ((unsigned)f2bf(f.w) << 16);
    *(uint2*)(out + i) = u;
  } else if (y == 4) {
    if (bx >= 4096) return;
    long i = bx * 1024 + threadIdx.x * 4;     // over 4*NW concatenated
    int j = (int)(i >> 20);
    const float* in = j == 0 ? Wv : j == 1 ? Wk : j == 2 ? Wq : Wm;
    long off = i & (NWC - 1);
    float4 f = *(const float4*)(in + off);
    uint2 u;
    u.x = (unsigned)f2bf(f.x) | ((unsigned)f2bf(f.y) << 16);
    u.y = (unsigned)f2bf(f.z) | ((unsigned)f2bf(f.w) << 16);
    *(uint2*)(w4 + i) = u;
  } else {
#pragma unroll
    for (int rep = 0; rep < 4; ++rep) {
      long i = (bx * 4 + rep) * 256 + threadIdx.x;  // over 2*NM
      const int* m = (i >= NMC) ? mask : absm;
      long off = i & (NMC - 1);
      u64 bset = __ballot(m[off] != 0);
      if ((threadIdx.x & 63) == 0) bits[i >> 6] = bset;
    }
  }
}

// ------- triple-batched projection GEMM: {v,k,q} @ {Wv,Wk,Wq}^T ----------
// 128x128 tile, BK=64, grid (192,8)=1536 blocks. gld16 + xor-cb LDS.
__global__ __launch_bounds__(256) void gemm_p3(const u16* __restrict__ Avk,
                                               const u16* __restrict__ Aq,
                                               const u16* __restrict__ W4,
                                               u16* __restrict__ Cb) {
  __shared__ u16 As[128 * 64];
  __shared__ u16 Bs[128 * 64];
  const int tid = threadIdx.x;
  const int wave = tid >> 6, lane = tid & 63;
  const int quad = lane >> 4, l16 = lane & 15;
  const int l7 = l16 & 7;
  const int sel = blockIdx.x >> 6;
  const int row0 = (blockIdx.x & 63) * 128, col0 = blockIdx.y * 128;
  const int wm = (wave >> 1) * 64, wn = (wave & 1) * 64;
  const int lrow = lane >> 3;
  const int scb = (lane & 7) ^ lrow;
  const int K = HS, N = HS;

  const u16* A = (sel == 2) ? Aq : Avk + (long)sel * NTOKC;
  const u16* W = W4 + (long)sel * NWC;
  u16* C = Cb + (long)sel * NTOKC;

  f32x4 acc[4][4];
#pragma unroll
  for (int mt = 0; mt < 4; ++mt)
#pragma unroll
    for (int nt = 0; nt < 4; ++nt) acc[mt][nt] = (f32x4){0.f, 0.f, 0.f, 0.f};

  const u16* Ab = A + (long)row0 * K;
  const u16* Wb = W + (long)col0 * K;

  for (int k0 = 0; k0 < K; k0 += 64) {
    __syncthreads();
#pragma unroll
    for (int it = 0; it < 4; ++it) {
      int seg = wave * 4 + it;
      int r = seg * 8 + lrow;
      gld16(Ab + (long)r * K + k0 + scb * 8, As + seg * 512);
      gld16(Wb + (long)r * K + k0 + scb * 8, Bs + seg * 512);
    }
    __syncthreads();
#pragma unroll
    for (int kt = 0; kt < 2; ++kt) {
      short8 af[4], bw[4];
#pragma unroll
      for (int mt = 0; mt < 4; ++mt)
        af[mt] = *(const short8*)(As + (wm + mt * 16 + l16) * 64 +
                                  (((kt * 4 + quad) ^ l7) * 8));
#pragma unroll
      for (int nt = 0; nt < 4; ++nt)
        bw[nt] = *(const short8*)(Bs + (wn + nt * 16 + l16) * 64 +
                                  (((kt * 4 + quad) ^ l7) * 8));
#pragma unroll
      for (int mt = 0; mt < 4; ++mt)
#pragma unroll
        for (int nt = 0; nt < 4; ++nt)
          acc[mt][nt] = __builtin_amdgcn_mfma_f32_16x16x32_bf16(
              af[mt], bw[nt], acc[mt][nt], 0, 0, 0);
    }
  }
#pragma unroll
  for (int mt = 0; mt < 4; ++mt)
#pragma unroll
    for (int nt = 0; nt < 4; ++nt)
#pragma unroll
      for (int i = 0; i < 4; ++i) {
        long r = row0 + wm + mt * 16 + quad * 4 + i;
        long c = col0 + wn + nt * 16 + l16;
        C[r * N + c] = f2bf(acc[mt][nt][i]);
      }
}

// ---------------- final GEMM: out[f32] = att @ Wm^T, 64x128 tile ----------
__global__ __launch_bounds__(256, 4) void gemm_f(const u16* __restrict__ A,
                                                 const u16* __restrict__ W,
                                                 float* __restrict__ C) {
  __shared__ u16 As[64 * 64];
  __shared__ u16 Bs[128 * 64];
  const int tid = threadIdx.x;
  const int wave = tid >> 6, lane = tid & 63;
  const int quad = lane >> 4, l16 = lane & 15;
  const int l7 = l16 & 7;
  const int row0 = blockIdx.x * 64, col0 = blockIdx.y * 128;
  const int wm = (wave >> 1) * 32, wn = (wave & 1) * 64;
  const int lrow = lane >> 3;
  const int scb = (lane & 7) ^ lrow;
  const int K = HS, N = HS;

  f32x4 acc[2][4];
#pragma unroll
  for (int mt = 0; mt < 2; ++mt)
#pragma unroll
    for (int nt = 0; nt < 4; ++nt) acc[mt][nt] = (f32x4){0.f, 0.f, 0.f, 0.f};

  const u16* Ab = A + (long)row0 * K;
  const u16* Wb = W + (long)col0 * K;

  for (int k0 = 0; k0 < K; k0 += 64) {
    __syncthreads();
#pragma unroll
    for (int it = 0; it < 2; ++it) {
      int seg = wave * 2 + it;
      gld16(Ab + (long)(seg * 8 + lrow) * K + k0 + scb * 8, As + seg * 512);
    }
#pragma unroll
    for (int it = 0; it < 4; ++it) {
      int seg = wave * 4 + it;
      gld16(Wb + (long)(seg * 8 + lrow) * K + k0 + scb * 8, Bs + seg * 512);
    }
    __syncthreads();
#pragma unroll
    for (int kt = 0; kt < 2; ++kt) {
      short8 af[2], bw[4];
#pragma unroll
      for (int mt = 0; mt < 2; ++mt)
        af[mt] = *(const short8*)(As + (wm + mt * 16 + l16) * 64 +
                                  (((kt * 4 + quad) ^ l7) * 8));
#pragma unroll
      for (int nt = 0; nt < 4; ++nt)
        bw[nt] = *(const short8*)(Bs + (wn + nt * 16 + l16) * 64 +
                                  (((kt * 4 + quad) ^ l7) * 8));
#pragma unroll
      for (int mt = 0; mt < 2; ++mt)
#pragma unroll
        for (int nt = 0; nt < 4; ++nt)
          acc[mt][nt] = __builtin_amdgcn_mfma_f32_16x16x32_bf16(
              af[mt], bw[nt], acc[mt][nt], 0, 0, 0);
    }
  }
#pragma unroll
  for (int mt = 0; mt < 2; ++mt)
#pragma unroll
    for (int nt = 0; nt < 4; ++nt)
#pragma unroll
      for (int i = 0; i < 4; ++i) {
        long r = row0 + wm + mt * 16 + quad * 4 + i;
        long c = col0 + wn + nt * 16 + l16;
        C[r * N + c] = acc[mt][nt][i];
      }
}

// ---------------- one attention stage: l,o += softmax-accum over 8 tiles --
// Register-prefetched K/V staging (tile t+1 loads issued under tile t's
// compute). 2 barriers/tile; NO barrier after P write (each wave reads only
// its own 16 Ps rows). Masked entries -> p=0 exactly; no max-tracking.
__device__ __forceinline__ void attn_stage(
    const u16* __restrict__ Kb, const u16* __restrict__ Vb,
    const u32* __restrict__ Mb, int q0, short8 qf[2], float l_i[4],
    f32x4 o[4], u16 (*Ks)[72], u16 (*Vs)[72], u16 (*Ps)[72],
    int wave, int quad, int l16, int sr, int sds, int vcol) {
  uint4 kp0 = *(const uint4*)(Kb + (long)sr * HS + sds);
  uint4 kp1 = *(const uint4*)(Kb + (long)sr * HS + sds + 8);
  uint4 vp0 = *(const uint4*)(Vb + (long)sr * HS + sds);
  uint4 vp1 = *(const uint4*)(Vb + (long)sr * HS + sds + 8);
  for (int t = 0; t < 8; ++t) {
    __syncthreads();  // WAR: all waves done with previous tile's Ks/Vs
    *(uint4*)&Ks[sr][sds] = kp0;
    *(uint4*)&Ks[sr][sds + 8] = kp1;
    {
      union { uint4 q[2]; u16 e[16]; } tv;
      tv.q[0] = vp0; tv.q[1] = vp1;
#pragma unroll
      for (int j = 0; j < 16; ++j) Vs[sds + j][vcol] = tv.e[j];
    }
    __syncthreads();  // staging visible
    if (t < 7) {      // prefetch tile t+1 under this tile's compute
      const u16* Kn = Kb + (long)((t + 1) * 64 + sr) * HS;
      kp0 = *(const uint4*)(Kn + sds);
      kp1 = *(const uint4*)(Kn + sds + 8);
      const u16* Vn = Vb + (long)((t + 1) * 64 + sr) * HS;
      vp0 = *(const uint4*)(Vn + sds);
      vp1 = *(const uint4*)(Vn + sds + 8);
    }
    // S = Q K^T
    f32x4 s[4];
#pragma unroll
    for (int nt = 0; nt < 4; ++nt) s[nt] = (f32x4){0.f, 0.f, 0.f, 0.f};
#pragma unroll
    for (int kt = 0; kt < 2; ++kt)
#pragma unroll
      for (int nt = 0; nt < 4; ++nt) {
        short8 bk = *(const short8*)&Ks[nt * 16 + l16][kt * 32 + quad * 8];
        s[nt] = __builtin_amdgcn_mfma_f32_16x16x32_bf16(qf[kt], bk, s[nt], 0, 0, 0);
      }
    // mask + exp + P write (wave-private Ps rows)
#pragma unroll
    for (int i = 0; i < 4; ++i) {
      int gr = q0 + wave * 16 + quad * 4 + i;
      uint2 mw = *(const uint2*)&Mb[(long)gr * 16 + t * 2];
#pragma unroll
      for (int nt = 0; nt < 4; ++nt) {
        u32 w = (nt & 2) ? mw.y : mw.x;
        int msk = (w >> ((nt & 1) * 16 + l16)) & 1;
        float p = msk ? 0.f : __expf(s[nt][i] * 0.125f);
        l_i[i] += p;
        Ps[wave * 16 + quad * 4 + i][nt * 16 + l16] = f2bf(p);
      }
    }
    // O += P V  (RAW on Ps is within-wave: lgkmcnt, no barrier)
#pragma unroll
    for (int kt = 0; kt < 2; ++kt) {
      short8 ap = *(const short8*)&Ps[wave * 16 + l16][kt * 32 + quad * 8];
#pragma unroll
      for (int nt = 0; nt < 4; ++nt) {
        short8 bv = *(const short8*)&Vs[nt * 16 + l16]
                                      [(kt * 32 + quad * 8) ^ ((nt & 3) << 4)];
        o[nt] = __builtin_amdgcn_mfma_f32_16x16x32_bf16(ap, bv, o[nt], 0, 0, 0);
      }
    }
  }
}

// ---------------- fused modulate+main attention ----------------
// One block = (b, h, 64-q rows), 2048 blocks, LDS 27.6KB -> 5 blocks/CU.
// Stage1: qm = Q + softmax(Q pb^T/8, abs)pb (qm stays in registers, A-layout
// via per-wave LDS transpose). Stage2: att = softmax(qm kh^T/8, mask) vh.
__global__ __launch_bounds__(256) void attn_fused(
    const u16* __restrict__ Qp, const u16* __restrict__ Pbp,
    const u16* __restrict__ Kp, const u16* __restrict__ Vp,
    const u32* __restrict__ B0, const u32* __restrict__ B1,
    u16* __restrict__ Op) {
  __shared__ u16 Ks[64][72];
  __shared__ u16 Vs[64][72];
  __shared__ u16 Ps[64][72];
  const int tid = threadIdx.x;
  const int wave = tid >> 6, lane = tid & 63;
  const int quad = lane >> 4, l16 = lane & 15;
  const int qt = blockIdx.x, h = blockIdx.y, b = blockIdx.z;
  const int q0 = qt * 64;
  const long bs = (long)SL * HS;
  const u16* Qb = Qp + (long)b * bs + h * HD;
  const u16* Pb = Pbp + (long)b * bs + h * HD;
  const u16* Kb = Kp + (long)b * bs + h * HD;
  const u16* Vb = Vp + (long)b * bs + h * HD;
  const u32* M0 = B0 + (long)b * SL * 16;
  const u32* M1 = B1 + (long)b * SL * 16;
  const int sr = tid >> 2, sds = (tid & 3) * 16;
  const int vcol = sr ^ (((sds >> 4) & 3) << 4);

  // Q A-frags -> registers
  short8 qf[2];
#pragma unroll
  for (int kt = 0; kt < 2; ++kt)
    qf[kt] = *(const short8*)(Qb + (long)(q0 + wave * 16 + l16) * HS +
                              kt * 32 + quad * 8);

  float l_i[4] = {0.f, 0.f, 0.f, 0.f};
  f32x4 o[4];
#pragma unroll
  for (int nt = 0; nt < 4; ++nt) o[nt] = (f32x4){0.f, 0.f, 0.f, 0.f};

  // ---- stage 1: modulate over img_abs (K = V = pb) ----
  attn_stage(Pb, Pb, M0, q0, qf, l_i, o, Ks, Vs, Ps, wave, quad, l16, sr, sds, vcol);

  // ---- qm = Q + O/l, rebuilt as A-layout frags via per-wave Ps transpose --
#pragma unroll
  for (int i = 0; i < 4; ++i) {
    float rs = l_i[i];
#pragma unroll
    for (int off = 8; off >= 1; off >>= 1) rs += __shfl_xor(rs, off, 64);
    float inv = 1.f / rs;
#pragma unroll
    for (int nt = 0; nt < 4; ++nt)
      Ps[wave * 16 + quad * 4 + i][nt * 16 + l16] = f2bf(o[nt][i] * inv);
    l_i[i] = 0.f;
  }
#pragma unroll
  for (int kt = 0; kt < 2; ++kt) {
    short8 t8 = *(const short8*)&Ps[wave * 16 + l16][kt * 32 + quad * 8];
#pragma unroll
    for (int j = 0; j < 8; ++j)
      qf[kt][j] = (short)f2bf(bf2f((u16)t8[j]) + bf2f((u16)qf[kt][j]));
  }
#pragma unroll
  for (int nt = 0; nt < 4; ++nt) o[nt] = (f32x4){0.f, 0.f, 0.f, 0.f};

  // ---- stage 2: main attention over kh/vh ----
  attn_stage(Kb, Vb, M1, q0, qf, l_i, o, Ks, Vs, Ps, wave, quad, l16, sr, sds, vcol);

  // ---- epilogue: att ----
  u16* Ob = Op + (long)b * bs + h * HD;
#pragma unroll
  for (int i = 0; i < 4; ++i) {
    float rs = l_i[i];
#pragma unroll
    for (int off = 8; off >= 1; off >>= 1) rs += __shfl_xor(rs, off, 64);
    float inv = 1.f / rs;
    int r = q0 + wave * 16 + quad * 4 + i;
#pragma unroll
    for (int nt = 0; nt < 4; ++nt)
      Ob[(long)r * HS + nt * 16 + l16] = f2bf(o[nt][i] * inv);
  }
}

extern "C" void kernel_launch(void* const* d_in, const int* in_sizes, int n_in,
                              void* d_out, int out_size, void* d_ws,
                              size_t ws_size, hipStream_t stream) {
  const float* v   = (const float*)d_in[0];
  const float* k   = (const float*)d_in[1];
  const float* q   = (const float*)d_in[2];
  const float* img = (const float*)d_in[3];
  const float* Wv  = (const float*)d_in[4];
  const float* Wk  = (const float*)d_in[5];
  const float* Wq  = (const float*)d_in[6];
  const float* Wm  = (const float*)d_in[7];
  const int* absm  = (const int*)d_in[8];
  const int* mask  = (const int*)d_in[9];
  float* out = (float*)d_out;

  const long NTOK = NTOKC;
  const long NW   = NWC;
  const long NM   = NMC;
  // d_out (33.5 MB) doubles as bf16 staging for v,k; consumed by gemm_p3
  // before gemm_f overwrites it.
  u16* ovk = (u16*)d_out;
  u16* ws  = (u16*)d_ws;
  u16* xq  = ws;              // q bf16 staging; att output after attn_fused
  u16* pb  = ws + 1 * NTOK;   // img_abs bf16
  u16* vh  = ws + 2 * NTOK;   // gemm_p3 C base (vh,kh,qh contiguous)
  u16* kh  = ws + 3 * NTOK;
  u16* qh  = ws + 4 * NTOK;
  u16* w4  = ws + 5 * NTOK;
  u64* bt0 = (u64*)(w4 + 4 * NW);
  u64* bt1 = bt0 + NM / 64;
  u16* att = xq;

  prep<<<dim3(8192, 6), 256, 0, stream>>>(v, k, q, img, Wv, Wk, Wq, Wm,
                                          absm, mask, ovk, xq, pb, w4, bt0);
  gemm_p3<<<dim3(192, 8), 256, 0, stream>>>(ovk, xq, w4, vh);
  attn_fused<<<dim3(SL / 64, NHEAD, NB), 256, 0, stream>>>(
      qh, pb, kh, vh, (const u32*)bt0, (const u32*)bt1, att);
  gemm_f<<<dim3(NB * SL / 64, HS / 128), 256, 0, stream>>>(att, w4 + 3 * NW, out);
}